// Round 4
// baseline (667.526 us; speedup 1.0000x reference)
//
#include <hip/hip_runtime.h>
#include <stdint.h>

#define L_DIM 2048
#define B_DIM 32
#define ENC_DIM 1024
#define M_DIM (L_DIM * B_DIM)

typedef __attribute__((ext_vector_type(4))) float f32x4;
typedef __attribute__((ext_vector_type(8))) short short8;
typedef __attribute__((ext_vector_type(4))) __bf16 bf16x4;

static __device__ __forceinline__ float fast_tanh(float x) {
  float cx = fminf(fmaxf(x, -15.f), 15.f);
  float e = __expf(2.f * cx);
  return (e - 1.f) * __frcp_rn(e + 1.f);
}

static __device__ __forceinline__ short bfs(float x) {
  return __builtin_bit_cast(short, (__bf16)x);
}

static __device__ __forceinline__ void load_lds16(const void* g, void* l) {
  __builtin_amdgcn_global_load_lds((const __attribute__((address_space(1))) void*)g,
                                   (__attribute__((address_space(3))) void*)l, 16, 0, 0);
}

// ---------------- W_enc [K=1024][N=1024] fp32  ->  WT [N][K] bf16 -----------------
__global__ __launch_bounds__(256) void k_wt(const float* __restrict__ W,
                                            unsigned short* __restrict__ WT) {
  __shared__ float tile[64][65];
  const int t = threadIdx.x;
  const int k0 = (blockIdx.x & 15) << 6, n0 = (blockIdx.x >> 4) << 6;
#pragma unroll
  for (int i = 0; i < 16; ++i) {
    int idx = t + (i << 8);
    tile[idx >> 6][idx & 63] = W[(size_t)(k0 + (idx >> 6)) * 1024 + n0 + (idx & 63)];
  }
  __syncthreads();
#pragma unroll
  for (int i = 0; i < 16; ++i) {
    int idx = t + (i << 8);
    int r = idx >> 6, c = idx & 63;
    WT[(size_t)(n0 + r) * 1024 + k0 + c] =
        __builtin_bit_cast(unsigned short, (__bf16)tile[c][r]);
  }
}

// ---------------- q partial: grid 64 = 8 a-blocks x 8 h-blocks, 128 thr -----------
__global__ __launch_bounds__(128) void k_qpart(const float* __restrict__ hidden,
                                               const float* __restrict__ Wh,
                                               float* __restrict__ pq) {
  const int ablk = blockIdx.x & 7, hblk = blockIdx.x >> 3;
  const int a = (ablk << 7) + threadIdx.x;
  float acc[32];
#pragma unroll
  for (int b = 0; b < 32; ++b) acc[b] = 0.f;
  const int h0 = hblk << 7;
  for (int h = h0; h < h0 + 128; ++h) {
    float wv = Wh[(size_t)h * 1024 + a];
#pragma unroll
    for (int b = 0; b < 32; ++b) acc[b] = fmaf(hidden[(b << 10) + h], wv, acc[b]);
  }
#pragma unroll
  for (int b = 0; b < 32; ++b) pq[((size_t)hblk << 15) + (b << 10) + a] = acc[b];
}

__global__ __launch_bounds__(256) void k_qred(const float* __restrict__ pq,
                                              const float* __restrict__ ba,
                                              float* __restrict__ q) {
  int i = blockIdx.x * 256 + threadIdx.x;  // 32768
  float s = ba[i & 1023];
#pragma unroll
  for (int j = 0; j < 8; ++j) s += pq[((size_t)j << 15) + i];
  q[i] = s;
}

// ---------------- fused keys-GEMM + tanh.v reduction ------------------------------
// "direct-A" structure: A-fragments (8 k-contiguous bf16/lane) load straight from
// global fp32 + in-register cvt — no A LDS stage at all. B double-buffered in LDS
// via global_load_lds (pre-swizzled source), ONE barrier per K-tile; A-loads issued
// before B-next stage so B prefetch stays in flight across compute (counted vmcnt).
// q folded into MFMA C-in. launch_bounds(256,2): 64 in-flight A regs + 64 acc,
// (256,3)=170 would spill (R2: spill cost +165us).
__global__ __launch_bounds__(256, 2) void k_logits(const float* __restrict__ enc,
                                                   const unsigned short* __restrict__ WT,
                                                   const float* __restrict__ qv,
                                                   const float* __restrict__ v,
                                                   float* __restrict__ pl) {
  __shared__ __align__(16) unsigned short Bs[2][128 * 64];
  __shared__ float red[2][128];

  const int tid = threadIdx.x;
  // XCD-aware mapping: all 8 n-blocks of an m-panel land on one XCD
  const int xcd = blockIdx.x & 7, slot = blockIdx.x >> 3;
  const int nblk = slot & 7;
  const int mblk = xcd + ((slot >> 3) << 3);
  const int row0 = mblk << 7;
  const int n0 = nblk << 7;

  const int w = tid >> 6, lane = tid & 63;
  const int wr = w >> 1, wc = w & 1;
  const int g = lane >> 4, rr = lane & 15;

  float vreg[4];
#pragma unroll
  for (int nf = 0; nf < 4; ++nf) vreg[nf] = v[n0 + wc * 64 + nf * 16 + rr];

  // seed accumulator with q[b][col]: C/D row = wr*64+mf*16+g*4+rg, b = row&31
  f32x4 acc[4][4];
#pragma unroll
  for (int mf = 0; mf < 4; ++mf)
#pragma unroll
    for (int nf = 0; nf < 4; ++nf)
#pragma unroll
      for (int rg = 0; rg < 4; ++rg) {
        int b = ((mf & 1) << 4) + (g << 2) + rg;
        acc[mf][nf][rg] = qv[((size_t)b << 10) + n0 + wc * 64 + nf * 16 + rr];
      }

  // A row base pointers: lane (g,rr), frag mf -> row0+wr*64+mf*16+rr, k-base g*8
  const float* aptr[4];
#pragma unroll
  for (int mf = 0; mf < 4; ++mf)
    aptr[mf] = enc + (((size_t)(row0 + wr * 64 + mf * 16 + rr)) << 10) + (g << 3);

  const int brow = lane >> 3, bjj = lane & 7;

  // prologue: stage B tile 0
#pragma unroll
  for (int c = 0; c < 4; ++c) {
    int nrow = w * 32 + c * 8 + brow;
    int blk = bjj ^ (brow & 7);
    const char* src = (const char*)WT + (((size_t)(n0 + nrow) << 10)) * 2 + (blk << 4);
    load_lds16(src, (void*)&Bs[0][(w * 32 + c * 8) * 64]);
  }
  __syncthreads();

  for (int kt = 0; kt < 16; ++kt) {
    const int cur = kt & 1;
    // 1) A-loads for tile kt (issued FIRST: their per-use waits leave B-next in flight)
    f32x4 alo[2][4], ahi[2][4];
#pragma unroll
    for (int kk = 0; kk < 2; ++kk)
#pragma unroll
      for (int mf = 0; mf < 4; ++mf) {
        const float* p = aptr[mf] + kt * 64 + kk * 32;
        alo[kk][mf] = *reinterpret_cast<const f32x4*>(p);
        ahi[kk][mf] = *reinterpret_cast<const f32x4*>(p + 4);
      }
    // 2) B stage for tile kt+1 into the other buffer (overlaps this tile's compute)
    if (kt < 15) {
#pragma unroll
      for (int c = 0; c < 4; ++c) {
        int nrow = w * 32 + c * 8 + brow;
        int blk = bjj ^ (brow & 7);
        const char* src =
            (const char*)WT + (((size_t)(n0 + nrow) << 10) + (kt + 1) * 64) * 2 + (blk << 4);
        load_lds16(src, (void*)&Bs[cur ^ 1][(w * 32 + c * 8) * 64]);
      }
    }
    // 3) compute tile kt: B-frags from LDS (swizzled), A-frags cvt in-register
#pragma unroll
    for (int kk = 0; kk < 2; ++kk) {
      short8 bfr[4];
#pragma unroll
      for (int nf = 0; nf < 4; ++nf) {
        int r = wc * 64 + nf * 16 + rr;
        int blk = (kk * 4 + g) ^ (r & 7);
        bfr[nf] = *reinterpret_cast<const short8*>(&Bs[cur][r * 64 + (blk << 3)]);
      }
#pragma unroll
      for (int mf = 0; mf < 4; ++mf) {
        f32x4 lo = alo[kk][mf], hi = ahi[kk][mf];
        short8 af;
        af[0] = bfs(lo.x); af[1] = bfs(lo.y); af[2] = bfs(lo.z); af[3] = bfs(lo.w);
        af[4] = bfs(hi.x); af[5] = bfs(hi.y); af[6] = bfs(hi.z); af[7] = bfs(hi.w);
#pragma unroll
        for (int nf = 0; nf < 4; ++nf)
          acc[mf][nf] = __builtin_amdgcn_mfma_f32_16x16x32_bf16(af, bfr[nf], acc[mf][nf], 0, 0, 0);
      }
    }
    __syncthreads();
  }

  // --- epilogue: tanh(S+q)*v, reduce over this block's 128 n-columns ---
#pragma unroll
  for (int mf = 0; mf < 4; ++mf) {
#pragma unroll
    for (int rg = 0; rg < 4; ++rg) {
      int lrow = wr * 64 + mf * 16 + g * 4 + rg;   // C/D: col=lane&15, row=4*(lane>>4)+reg
      float s = 0.f;
#pragma unroll
      for (int nf = 0; nf < 4; ++nf) {
        s += fast_tanh(acc[mf][nf][rg]) * vreg[nf];
      }
      s += __shfl_xor(s, 1);
      s += __shfl_xor(s, 2);
      s += __shfl_xor(s, 4);
      s += __shfl_xor(s, 8);
      if (rr == 0) red[wc][lrow] = s;
    }
  }
  __syncthreads();
  if (tid < 128) {
    int row = row0 + tid;                          // row = l*32 + b
    pl[((size_t)nblk << 16) + ((size_t)(row & 31) << 11) + (row >> 5)] =
        red[0][tid] + red[1][tid];
  }
}

// ---------------- softmax over l, per b ------------------------------------------
__global__ __launch_bounds__(256) void k_softmax(const float* __restrict__ pl,
                                                 const float* __restrict__ mask,
                                                 float* __restrict__ al) {
  const int b = blockIdx.x, t = threadIdx.x;
  __shared__ float sr[256];
  float lg[8];
  float mx = -3.4e38f;
#pragma unroll
  for (int i = 0; i < 8; ++i) {
    int l = t + (i << 8);
    float s = mask[(l << 5) + b];
#pragma unroll
    for (int nb = 0; nb < 8; ++nb) s += pl[((size_t)nb << 16) + (b << 11) + l];
    lg[i] = s;
    mx = fmaxf(mx, s);
  }
  sr[t] = mx;
  __syncthreads();
  for (int off = 128; off > 0; off >>= 1) {
    if (t < off) sr[t] = fmaxf(sr[t], sr[t + off]);
    __syncthreads();
  }
  const float M = sr[0];
  __syncthreads();
  float sum = 0.f;
#pragma unroll
  for (int i = 0; i < 8; ++i) {
    lg[i] = __expf(lg[i] - M);
    sum += lg[i];
  }
  sr[t] = sum;
  __syncthreads();
  for (int off = 128; off > 0; off >>= 1) {
    if (t < off) sr[t] += sr[t + off];
    __syncthreads();
  }
  const float inv = 1.f / sr[0];
#pragma unroll
  for (int i = 0; i < 8; ++i) {
    int l = t + (i << 8);
    al[(l << 5) + b] = lg[i] * inv;
  }
}

// ---------------- context partials: grid = 32 chunks x 32 b ----------------------
__global__ __launch_bounds__(256) void k_ctx(const float* __restrict__ enc,
                                             const float* __restrict__ al,
                                             float* __restrict__ pctx) {
  const int b = blockIdx.x & 31, ch = blockIdx.x >> 5;
  const int t = threadIdx.x;
  __shared__ float wl[64];
  if (t < 64) wl[t] = al[(((ch << 6) + t) << 5) + b];
  __syncthreads();
  f32x4 acc = (f32x4){0.f, 0.f, 0.f, 0.f};
  const float* base = enc + (((size_t)ch * 2048 + b) << 10) + (t << 2);
#pragma unroll 8
  for (int i = 0; i < 64; ++i) {
    f32x4 e = *reinterpret_cast<const f32x4*>(base + (size_t)i * 32768);
    acc += wl[i] * e;
  }
  *reinterpret_cast<f32x4*>(((float*)pctx) + ((size_t)blockIdx.x << 10) + (t << 2)) = acc;
}

__global__ __launch_bounds__(256) void k_ctxred(const float* __restrict__ pctx,
                                                float* __restrict__ out) {
  int i = blockIdx.x * 256 + threadIdx.x;  // 32768 = b*1024 + e
  int b = i >> 10, e = i & 1023;
  float s = 0.f;
#pragma unroll
  for (int ch = 0; ch < 32; ++ch) s += pctx[(size_t)((ch << 5) + b) * 1024 + e];
  out[i] = s;
}

extern "C" void kernel_launch(void* const* d_in, const int* in_sizes, int n_in,
                              void* d_out, int out_size, void* d_ws, size_t ws_size,
                              hipStream_t stream) {
  const float* enc = (const float*)d_in[0];
  const float* mask = (const float*)d_in[1];
  const float* hidden = (const float*)d_in[2];
  const float* Wenc = (const float*)d_in[3];
  const float* battn = (const float*)d_in[4];
  const float* Whid = (const float*)d_in[5];
  const float* v = (const float*)d_in[6];
  float* out = (float*)d_out;          // [0,32768) context [B][ENC]; [32768,98304) alignment [L][B]
  char* ws = (char*)d_ws;

  unsigned short* WT = (unsigned short*)ws;                       // 2 MB
  float* q = (float*)(ws + (2u << 20));                           // 128 KB
  float* pq = (float*)(ws + (2u << 20) + (128u << 10));           // 1 MB
  float* pl = (float*)(ws + (3u << 20) + (128u << 10));           // 2 MB
  float* pctx = (float*)(ws + (5u << 20) + (128u << 10));         // 4 MB
  float* align_out = out + 32768;

  k_wt<<<256, 256, 0, stream>>>(Wenc, WT);
  k_qpart<<<64, 128, 0, stream>>>(hidden, Whid, pq);
  k_qred<<<128, 256, 0, stream>>>(pq, battn, q);
  k_logits<<<4096, 256, 0, stream>>>(enc, WT, q, v, pl);
  k_softmax<<<32, 256, 0, stream>>>(pl, mask, align_out);
  k_ctx<<<1024, 256, 0, stream>>>(enc, align_out, pctx);
  k_ctxred<<<128, 256, 0, stream>>>(pctx, out);
}

// Round 5
// 370.004 us; speedup vs baseline: 1.8041x; 1.8041x over previous
//
#include <hip/hip_runtime.h>
#include <stdint.h>

#define L_DIM 2048
#define B_DIM 32
#define ENC_DIM 1024
#define M_DIM (L_DIM * B_DIM)

typedef __attribute__((ext_vector_type(4))) float f32x4;
typedef __attribute__((ext_vector_type(4))) unsigned int uint4v;
typedef __attribute__((ext_vector_type(8))) short short8;
typedef __attribute__((ext_vector_type(4))) __bf16 bf16x4;

static __device__ __forceinline__ float fast_tanh(float x) {
  float cx = fminf(fmaxf(x, -15.f), 15.f);
  float e = __expf(2.f * cx);
  return (e - 1.f) * __frcp_rn(e + 1.f);
}

static __device__ __forceinline__ void load_lds16(const void* g, void* l) {
  __builtin_amdgcn_global_load_lds((const __attribute__((address_space(1))) void*)g,
                                   (__attribute__((address_space(3))) void*)l, 16, 0, 0);
}

// ---------------- enc fp32 -> bf16 copy (64M elems) -------------------------------
__global__ __launch_bounds__(256) void k_enc_bf16(const float* __restrict__ enc,
                                                  unsigned short* __restrict__ encB) {
  const int t = blockIdx.x * 256 + threadIdx.x;   // 524288 threads
#pragma unroll
  for (int it = 0; it < 16; ++it) {
    size_t i = ((size_t)t + (size_t)it * 524288) << 3;   // 8 floats per thread-iter
    f32x4 a = *reinterpret_cast<const f32x4*>(enc + i);
    f32x4 b = *reinterpret_cast<const f32x4*>(enc + i + 4);
    bf16x4 pa = {(__bf16)a.x, (__bf16)a.y, (__bf16)a.z, (__bf16)a.w};
    bf16x4 pb = {(__bf16)b.x, (__bf16)b.y, (__bf16)b.z, (__bf16)b.w};
    uint4v o;
    o.x = __builtin_bit_cast(unsigned int, *reinterpret_cast<ushort2*>(&pa));
    // pack via memory-safe bit_cast of halves
    union { bf16x4 v; unsigned int u[2]; } ua, ub;
    ua.v = pa; ub.v = pb;
    o.x = ua.u[0]; o.y = ua.u[1]; o.z = ub.u[0]; o.w = ub.u[1];
    *reinterpret_cast<uint4v*>(encB + i) = o;
  }
}

// ---------------- W_enc [K=1024][N=1024] fp32  ->  WT [N][K] bf16 -----------------
__global__ __launch_bounds__(256) void k_wt(const float* __restrict__ W,
                                            unsigned short* __restrict__ WT) {
  __shared__ float tile[64][65];
  const int t = threadIdx.x;
  const int k0 = (blockIdx.x & 15) << 6, n0 = (blockIdx.x >> 4) << 6;
#pragma unroll
  for (int i = 0; i < 16; ++i) {
    int idx = t + (i << 8);
    tile[idx >> 6][idx & 63] = W[(size_t)(k0 + (idx >> 6)) * 1024 + n0 + (idx & 63)];
  }
  __syncthreads();
#pragma unroll
  for (int i = 0; i < 16; ++i) {
    int idx = t + (i << 8);
    int r = idx >> 6, c = idx & 63;
    WT[(size_t)(n0 + r) * 1024 + k0 + c] =
        __builtin_bit_cast(unsigned short, (__bf16)tile[c][r]);
  }
}

// ---------------- q partial: grid 64 = 8 a-blocks x 8 h-blocks, 128 thr -----------
__global__ __launch_bounds__(128) void k_qpart(const float* __restrict__ hidden,
                                               const float* __restrict__ Wh,
                                               float* __restrict__ pq) {
  const int ablk = blockIdx.x & 7, hblk = blockIdx.x >> 3;
  const int a = (ablk << 7) + threadIdx.x;
  float acc[32];
#pragma unroll
  for (int b = 0; b < 32; ++b) acc[b] = 0.f;
  const int h0 = hblk << 7;
  for (int h = h0; h < h0 + 128; ++h) {
    float wv = Wh[(size_t)h * 1024 + a];
#pragma unroll
    for (int b = 0; b < 32; ++b) acc[b] = fmaf(hidden[(b << 10) + h], wv, acc[b]);
  }
#pragma unroll
  for (int b = 0; b < 32; ++b) pq[((size_t)hblk << 15) + (b << 10) + a] = acc[b];
}

__global__ __launch_bounds__(256) void k_qred(const float* __restrict__ pq,
                                              const float* __restrict__ ba,
                                              float* __restrict__ q) {
  int i = blockIdx.x * 256 + threadIdx.x;  // 32768
  float s = ba[i & 1023];
#pragma unroll
  for (int j = 0; j < 8; ++j) s += pq[((size_t)j << 15) + i];
  q[i] = s;
}

// ================= fused keys-GEMM + tanh.v reduction ============================
// Shared epilogue/geometry for both variants. 128x128 tile, BK=64, 4 waves,
// q folded into MFMA C-in, pl[nblk][b][l] transposed partial-logit output.

// ---- variant A (big ws): A and B both bf16, staged via global_load_lds width-16
//      with pre-swizzled sources (m97 structure).
__global__ __launch_bounds__(256, 3) void k_logits_bf(const unsigned short* __restrict__ encB,
                                                      const unsigned short* __restrict__ WT,
                                                      const float* __restrict__ qv,
                                                      const float* __restrict__ v,
                                                      float* __restrict__ pl) {
  __shared__ __align__(16) unsigned short As[128 * 64];
  __shared__ __align__(16) unsigned short Bs[128 * 64];
  __shared__ float red[2][128];

  const int tid = threadIdx.x;
  const int xcd = blockIdx.x & 7, slot = blockIdx.x >> 3;
  const int nblk = slot & 7;
  const int mblk = xcd + ((slot >> 3) << 3);
  const int row0 = mblk << 7;
  const int n0 = nblk << 7;

  const int w = tid >> 6, lane = tid & 63;
  const int wr = w >> 1, wc = w & 1;
  const int g = lane >> 4, rr = lane & 15;

  float vreg[4];
#pragma unroll
  for (int nf = 0; nf < 4; ++nf) vreg[nf] = v[n0 + wc * 64 + nf * 16 + rr];

  f32x4 acc[4][4];
#pragma unroll
  for (int mf = 0; mf < 4; ++mf)
#pragma unroll
    for (int nf = 0; nf < 4; ++nf)
#pragma unroll
      for (int rg = 0; rg < 4; ++rg) {
        int b = ((mf & 1) << 4) + (g << 2) + rg;
        acc[mf][nf][rg] = qv[((size_t)b << 10) + n0 + wc * 64 + nf * 16 + rr];
      }

  const int srow = lane >> 3, sjj = lane & 7;   // staging row-offset / 16B-block

  for (int kt = 0; kt < 16; ++kt) {
    const int k0 = kt << 6;
    __syncthreads();
#pragma unroll
    for (int c = 0; c < 4; ++c) {
      int r = w * 32 + c * 8 + srow;
      int blk = sjj ^ (r & 7);
      // B tile (WT rows are n)
      const char* bsrc = (const char*)WT + (((size_t)(n0 + r) << 10) + k0) * 2 + (blk << 4);
      load_lds16(bsrc, (void*)&Bs[(w * 32 + c * 8) * 64]);
      // A tile (encB rows are m)
      const char* asrc = (const char*)encB + (((size_t)(row0 + r) << 10) + k0) * 2 + (blk << 4);
      load_lds16(asrc, (void*)&As[(w * 32 + c * 8) * 64]);
    }
    __syncthreads();
#pragma unroll
    for (int kk = 0; kk < 2; ++kk) {
      short8 af[4], bfr[4];
#pragma unroll
      for (int mf = 0; mf < 4; ++mf) {
        int r = wr * 64 + mf * 16 + rr;
        int blk = (kk * 4 + g) ^ (r & 7);
        af[mf] = *reinterpret_cast<const short8*>(&As[r * 64 + (blk << 3)]);
      }
#pragma unroll
      for (int nf = 0; nf < 4; ++nf) {
        int r = wc * 64 + nf * 16 + rr;
        int blk = (kk * 4 + g) ^ (r & 7);
        bfr[nf] = *reinterpret_cast<const short8*>(&Bs[r * 64 + (blk << 3)]);
      }
#pragma unroll
      for (int mf = 0; mf < 4; ++mf)
#pragma unroll
        for (int nf = 0; nf < 4; ++nf)
          acc[mf][nf] = __builtin_amdgcn_mfma_f32_16x16x32_bf16(af[mf], bfr[nf], acc[mf][nf], 0, 0, 0);
    }
  }

#pragma unroll
  for (int mf = 0; mf < 4; ++mf) {
#pragma unroll
    for (int rg = 0; rg < 4; ++rg) {
      int lrow = wr * 64 + mf * 16 + g * 4 + rg;
      float s = 0.f;
#pragma unroll
      for (int nf = 0; nf < 4; ++nf) s += fast_tanh(acc[mf][nf][rg]) * vreg[nf];
      s += __shfl_xor(s, 1);
      s += __shfl_xor(s, 2);
      s += __shfl_xor(s, 4);
      s += __shfl_xor(s, 8);
      if (rr == 0) red[wc][lrow] = s;
    }
  }
  __syncthreads();
  if (tid < 128) {
    int row = row0 + tid;
    pl[((size_t)nblk << 16) + ((size_t)(row & 31) << 11) + (row >> 5)] =
        red[0][tid] + red[1][tid];
  }
}

// ---- variant B (fallback, small ws): exact R3 kernel — A fp32->cvt->ds_write ----
__global__ __launch_bounds__(256, 3) void k_logits_cvt(const float* __restrict__ enc,
                                                       const unsigned short* __restrict__ WT,
                                                       const float* __restrict__ qv,
                                                       const float* __restrict__ v,
                                                       float* __restrict__ pl) {
  __shared__ __align__(16) unsigned short As[128 * 64];
  __shared__ __align__(16) unsigned short Bs[128 * 64];
  __shared__ float red[2][128];

  const int tid = threadIdx.x;
  const int xcd = blockIdx.x & 7, slot = blockIdx.x >> 3;
  const int nblk = slot & 7;
  const int mblk = xcd + ((slot >> 3) << 3);
  const int row0 = mblk << 7;
  const int n0 = nblk << 7;

  const int w = tid >> 6, lane = tid & 63;
  const int wr = w >> 1, wc = w & 1;
  const int g = lane >> 4, rr = lane & 15;

  float vreg[4];
#pragma unroll
  for (int nf = 0; nf < 4; ++nf) vreg[nf] = v[n0 + wc * 64 + nf * 16 + rr];

  f32x4 acc[4][4];
#pragma unroll
  for (int mf = 0; mf < 4; ++mf)
#pragma unroll
    for (int nf = 0; nf < 4; ++nf)
#pragma unroll
      for (int rg = 0; rg < 4; ++rg) {
        int b = ((mf & 1) << 4) + (g << 2) + rg;
        acc[mf][nf][rg] = qv[((size_t)b << 10) + n0 + wc * 64 + nf * 16 + rr];
      }

  const int ar = tid >> 4;
  const int ac4 = tid & 15;
  const int ablk = ((ac4 >> 1) ^ (ar & 7));
  const int brow = lane >> 3, bjj = lane & 7;

  for (int kt = 0; kt < 16; ++kt) {
    const int k0 = kt << 6;
    __syncthreads();
#pragma unroll
    for (int c = 0; c < 4; ++c) {
      int nrow = w * 32 + c * 8 + brow;
      int blk = bjj ^ (brow & 7);
      const char* src = (const char*)WT + (((size_t)(n0 + nrow) << 10) + k0) * 2 + (blk << 4);
      load_lds16(src, (void*)&Bs[(w * 32 + c * 8) * 64]);
    }
#pragma unroll
    for (int i = 0; i < 8; ++i) {
      int r = ar + (i << 4);
      f32x4 a4 = *reinterpret_cast<const f32x4*>(enc + (((size_t)(row0 + r)) << 10) + k0 + (ac4 << 2));
      bf16x4 pk = {(__bf16)a4.x, (__bf16)a4.y, (__bf16)a4.z, (__bf16)a4.w};
      *reinterpret_cast<bf16x4*>(&As[r * 64 + (ablk << 3) + ((ac4 & 1) << 2)]) = pk;
    }
    __syncthreads();
#pragma unroll
    for (int kk = 0; kk < 2; ++kk) {
      short8 af[4], bfr[4];
#pragma unroll
      for (int mf = 0; mf < 4; ++mf) {
        int r = wr * 64 + mf * 16 + rr;
        int blk = (kk * 4 + g) ^ (r & 7);
        af[mf] = *reinterpret_cast<const short8*>(&As[r * 64 + (blk << 3)]);
      }
#pragma unroll
      for (int nf = 0; nf < 4; ++nf) {
        int r = wc * 64 + nf * 16 + rr;
        int blk = (kk * 4 + g) ^ (r & 7);
        bfr[nf] = *reinterpret_cast<const short8*>(&Bs[r * 64 + (blk << 3)]);
      }
#pragma unroll
      for (int mf = 0; mf < 4; ++mf)
#pragma unroll
        for (int nf = 0; nf < 4; ++nf)
          acc[mf][nf] = __builtin_amdgcn_mfma_f32_16x16x32_bf16(af[mf], bfr[nf], acc[mf][nf], 0, 0, 0);
    }
  }

#pragma unroll
  for (int mf = 0; mf < 4; ++mf) {
#pragma unroll
    for (int rg = 0; rg < 4; ++rg) {
      int lrow = wr * 64 + mf * 16 + g * 4 + rg;
      float s = 0.f;
#pragma unroll
      for (int nf = 0; nf < 4; ++nf) s += fast_tanh(acc[mf][nf][rg]) * vreg[nf];
      s += __shfl_xor(s, 1);
      s += __shfl_xor(s, 2);
      s += __shfl_xor(s, 4);
      s += __shfl_xor(s, 8);
      if (rr == 0) red[wc][lrow] = s;
    }
  }
  __syncthreads();
  if (tid < 128) {
    int row = row0 + tid;
    pl[((size_t)nblk << 16) + ((size_t)(row & 31) << 11) + (row >> 5)] =
        red[0][tid] + red[1][tid];
  }
}

// ---------------- softmax over l, per b ------------------------------------------
__global__ __launch_bounds__(256) void k_softmax(const float* __restrict__ pl,
                                                 const float* __restrict__ mask,
                                                 float* __restrict__ al) {
  const int b = blockIdx.x, t = threadIdx.x;
  __shared__ float sr[256];
  float lg[8];
  float mx = -3.4e38f;
#pragma unroll
  for (int i = 0; i < 8; ++i) {
    int l = t + (i << 8);
    float s = mask[(l << 5) + b];
#pragma unroll
    for (int nb = 0; nb < 8; ++nb) s += pl[((size_t)nb << 16) + (b << 11) + l];
    lg[i] = s;
    mx = fmaxf(mx, s);
  }
  sr[t] = mx;
  __syncthreads();
  for (int off = 128; off > 0; off >>= 1) {
    if (t < off) sr[t] = fmaxf(sr[t], sr[t + off]);
    __syncthreads();
  }
  const float M = sr[0];
  __syncthreads();
  float sum = 0.f;
#pragma unroll
  for (int i = 0; i < 8; ++i) {
    lg[i] = __expf(lg[i] - M);
    sum += lg[i];
  }
  sr[t] = sum;
  __syncthreads();
  for (int off = 128; off > 0; off >>= 1) {
    if (t < off) sr[t] += sr[t + off];
    __syncthreads();
  }
  const float inv = 1.f / sr[0];
#pragma unroll
  for (int i = 0; i < 8; ++i) {
    int l = t + (i << 8);
    al[(l << 5) + b] = lg[i] * inv;
  }
}

// ---------------- context partials: grid = 32 chunks x 32 b ----------------------
__global__ __launch_bounds__(256) void k_ctx(const float* __restrict__ enc,
                                             const float* __restrict__ al,
                                             float* __restrict__ pctx) {
  const int b = blockIdx.x & 31, ch = blockIdx.x >> 5;
  const int t = threadIdx.x;
  __shared__ float wl[64];
  if (t < 64) wl[t] = al[(((ch << 6) + t) << 5) + b];
  __syncthreads();
  f32x4 acc = (f32x4){0.f, 0.f, 0.f, 0.f};
  const float* base = enc + (((size_t)ch * 2048 + b) << 10) + (t << 2);
#pragma unroll 8
  for (int i = 0; i < 64; ++i) {
    f32x4 e = *reinterpret_cast<const f32x4*>(base + (size_t)i * 32768);
    acc += wl[i] * e;
  }
  *reinterpret_cast<f32x4*>(((float*)pctx) + ((size_t)blockIdx.x << 10) + (t << 2)) = acc;
}

__global__ __launch_bounds__(256) void k_ctxred(const float* __restrict__ pctx,
                                                float* __restrict__ out) {
  int i = blockIdx.x * 256 + threadIdx.x;  // 32768 = b*1024 + e
  int b = i >> 10, e = i & 1023;
  float s = 0.f;
#pragma unroll
  for (int ch = 0; ch < 32; ++ch) s += pctx[(size_t)((ch << 5) + b) * 1024 + e];
  out[i] = s;
}

extern "C" void kernel_launch(void* const* d_in, const int* in_sizes, int n_in,
                              void* d_out, int out_size, void* d_ws, size_t ws_size,
                              hipStream_t stream) {
  const float* enc = (const float*)d_in[0];
  const float* mask = (const float*)d_in[1];
  const float* hidden = (const float*)d_in[2];
  const float* Wenc = (const float*)d_in[3];
  const float* battn = (const float*)d_in[4];
  const float* Whid = (const float*)d_in[5];
  const float* v = (const float*)d_in[6];
  float* out = (float*)d_out;          // [0,32768) context [B][ENC]; [32768,98304) alignment [L][B]
  char* ws = (char*)d_ws;

  const bool big = ws_size >= (size_t)140 * 1024 * 1024;
  // big layout: encB [0,128M); small buffers after. fallback layout: from 0.
  char* base = big ? ws + ((size_t)128 << 20) : ws;
  unsigned short* encB = (unsigned short*)ws;                       // 128 MB (big only)
  unsigned short* WT = (unsigned short*)base;                       // 2 MB
  float* q = (float*)(base + (2u << 20));                           // 128 KB
  float* pq = (float*)(base + (2u << 20) + (128u << 10));           // 1 MB
  float* pl = (float*)(base + (3u << 20) + (128u << 10));           // 2 MB
  float* pctx = (float*)(base + (5u << 20) + (128u << 10));         // 4 MB
  float* align_out = out + 32768;

  k_wt<<<256, 256, 0, stream>>>(Wenc, WT);
  k_qpart<<<64, 128, 0, stream>>>(hidden, Whid, pq);
  k_qred<<<128, 256, 0, stream>>>(pq, battn, q);
  if (big) {
    k_enc_bf16<<<2048, 256, 0, stream>>>(enc, encB);
    k_logits_bf<<<4096, 256, 0, stream>>>(encB, WT, q, v, pl);
  } else {
    k_logits_cvt<<<4096, 256, 0, stream>>>(enc, WT, q, v, pl);
  }
  k_softmax<<<32, 256, 0, stream>>>(pl, mask, align_out);
  k_ctx<<<1024, 256, 0, stream>>>(enc, align_out, pctx);
  k_ctxred<<<128, 256, 0, stream>>>(pctx, out);
}

// Round 6
// 338.176 us; speedup vs baseline: 1.9739x; 1.0941x over previous
//
#include <hip/hip_runtime.h>
#include <stdint.h>

#define L_DIM 2048
#define B_DIM 32
#define ENC_DIM 1024
#define M_DIM (L_DIM * B_DIM)

typedef __attribute__((ext_vector_type(4))) float f32x4;
typedef __attribute__((ext_vector_type(4))) unsigned int uint4v;
typedef __attribute__((ext_vector_type(8))) short short8;
typedef __attribute__((ext_vector_type(4))) short short4v;
typedef __attribute__((ext_vector_type(4))) __bf16 bf16x4;

static __device__ __forceinline__ float fast_tanh(float x) {
  float cx = fminf(fmaxf(x, -15.f), 15.f);
  float e = __expf(2.f * cx);
  return (e - 1.f) * __frcp_rn(e + 1.f);
}

static __device__ __forceinline__ float bf2f(unsigned short u) {
  return __builtin_bit_cast(float, (unsigned int)u << 16);
}

static __device__ __forceinline__ void load_lds16(const void* g, void* l) {
  __builtin_amdgcn_global_load_lds((const __attribute__((address_space(1))) void*)g,
                                   (__attribute__((address_space(3))) void*)l, 16, 0, 0);
}

// ---------------- enc fp32 -> bf16 copy (64M elems) -------------------------------
__global__ __launch_bounds__(256) void k_enc_bf16(const float* __restrict__ enc,
                                                  unsigned short* __restrict__ encB) {
  const int t = blockIdx.x * 256 + threadIdx.x;   // 524288 threads
#pragma unroll
  for (int it = 0; it < 16; ++it) {
    size_t i = ((size_t)t + (size_t)it * 524288) << 3;   // 8 floats per thread-iter
    f32x4 a = *reinterpret_cast<const f32x4*>(enc + i);
    f32x4 b = *reinterpret_cast<const f32x4*>(enc + i + 4);
    bf16x4 pa = {(__bf16)a.x, (__bf16)a.y, (__bf16)a.z, (__bf16)a.w};
    bf16x4 pb = {(__bf16)b.x, (__bf16)b.y, (__bf16)b.z, (__bf16)b.w};
    union { bf16x4 v; unsigned int u[2]; } ua, ub;
    ua.v = pa; ub.v = pb;
    uint4v o;
    o.x = ua.u[0]; o.y = ua.u[1]; o.z = ub.u[0]; o.w = ub.u[1];
    *reinterpret_cast<uint4v*>(encB + i) = o;
  }
}

// ---------------- W_enc [K=1024][N=1024] fp32  ->  WT [N][K] bf16 -----------------
__global__ __launch_bounds__(256) void k_wt(const float* __restrict__ W,
                                            unsigned short* __restrict__ WT) {
  __shared__ float tile[64][65];
  const int t = threadIdx.x;
  const int k0 = (blockIdx.x & 15) << 6, n0 = (blockIdx.x >> 4) << 6;
#pragma unroll
  for (int i = 0; i < 16; ++i) {
    int idx = t + (i << 8);
    tile[idx >> 6][idx & 63] = W[(size_t)(k0 + (idx >> 6)) * 1024 + n0 + (idx & 63)];
  }
  __syncthreads();
#pragma unroll
  for (int i = 0; i < 16; ++i) {
    int idx = t + (i << 8);
    int r = idx >> 6, c = idx & 63;
    WT[(size_t)(n0 + r) * 1024 + k0 + c] =
        __builtin_bit_cast(unsigned short, (__bf16)tile[c][r]);
  }
}

// ---------------- q partial: grid 64 = 8 a-blocks x 8 h-blocks, 128 thr -----------
__global__ __launch_bounds__(128) void k_qpart(const float* __restrict__ hidden,
                                               const float* __restrict__ Wh,
                                               float* __restrict__ pq) {
  const int ablk = blockIdx.x & 7, hblk = blockIdx.x >> 3;
  const int a = (ablk << 7) + threadIdx.x;
  float acc[32];
#pragma unroll
  for (int b = 0; b < 32; ++b) acc[b] = 0.f;
  const int h0 = hblk << 7;
  for (int h = h0; h < h0 + 128; ++h) {
    float wv = Wh[(size_t)h * 1024 + a];
#pragma unroll
    for (int b = 0; b < 32; ++b) acc[b] = fmaf(hidden[(b << 10) + h], wv, acc[b]);
  }
#pragma unroll
  for (int b = 0; b < 32; ++b) pq[((size_t)hblk << 15) + (b << 10) + a] = acc[b];
}

__global__ __launch_bounds__(256) void k_qred(const float* __restrict__ pq,
                                              const float* __restrict__ ba,
                                              float* __restrict__ q) {
  int i = blockIdx.x * 256 + threadIdx.x;  // 32768
  float s = ba[i & 1023];
#pragma unroll
  for (int j = 0; j < 8; ++j) s += pq[((size_t)j << 15) + i];
  q[i] = s;
}

// ================= fused keys-GEMM + tanh.v reduction ============================
// 128x128 tile, BK=64, 4 waves, q folded into MFMA C-in,
// pl[nblk][b][l] transposed partial-logit output.

// ---- variant A (big ws): A and B both bf16, staged via global_load_lds width-16
//      with pre-swizzled sources (m97 structure).
//      (256,4): arch VGPR=64 + 64 AGPR = 128 unified fits 4 waves/EU exactly;
//      tripwire = WRITE_SIZE (spill scratch) — revert to (256,3) if it balloons.
__global__ __launch_bounds__(256, 4) void k_logits_bf(const unsigned short* __restrict__ encB,
                                                      const unsigned short* __restrict__ WT,
                                                      const float* __restrict__ qv,
                                                      const float* __restrict__ v,
                                                      float* __restrict__ pl) {
  __shared__ __align__(16) unsigned short As[128 * 64];
  __shared__ __align__(16) unsigned short Bs[128 * 64];
  __shared__ float red[2][128];

  const int tid = threadIdx.x;
  const int xcd = blockIdx.x & 7, slot = blockIdx.x >> 3;
  const int nblk = slot & 7;
  const int mblk = xcd + ((slot >> 3) << 3);
  const int row0 = mblk << 7;
  const int n0 = nblk << 7;

  const int w = tid >> 6, lane = tid & 63;
  const int wr = w >> 1, wc = w & 1;
  const int g = lane >> 4, rr = lane & 15;

  float vreg[4];
#pragma unroll
  for (int nf = 0; nf < 4; ++nf) vreg[nf] = v[n0 + wc * 64 + nf * 16 + rr];

  f32x4 acc[4][4];
#pragma unroll
  for (int mf = 0; mf < 4; ++mf)
#pragma unroll
    for (int nf = 0; nf < 4; ++nf)
#pragma unroll
      for (int rg = 0; rg < 4; ++rg) {
        int b = ((mf & 1) << 4) + (g << 2) + rg;
        acc[mf][nf][rg] = qv[((size_t)b << 10) + n0 + wc * 64 + nf * 16 + rr];
      }

  const int srow = lane >> 3, sjj = lane & 7;   // staging row-offset / 16B-block

  for (int kt = 0; kt < 16; ++kt) {
    const int k0 = kt << 6;
    __syncthreads();
#pragma unroll
    for (int c = 0; c < 4; ++c) {
      int r = w * 32 + c * 8 + srow;
      int blk = sjj ^ (r & 7);
      const char* bsrc = (const char*)WT + (((size_t)(n0 + r) << 10) + k0) * 2 + (blk << 4);
      load_lds16(bsrc, (void*)&Bs[(w * 32 + c * 8) * 64]);
      const char* asrc = (const char*)encB + (((size_t)(row0 + r) << 10) + k0) * 2 + (blk << 4);
      load_lds16(asrc, (void*)&As[(w * 32 + c * 8) * 64]);
    }
    __syncthreads();
#pragma unroll
    for (int kk = 0; kk < 2; ++kk) {
      short8 af[4], bfr[4];
#pragma unroll
      for (int mf = 0; mf < 4; ++mf) {
        int r = wr * 64 + mf * 16 + rr;
        int blk = (kk * 4 + g) ^ (r & 7);
        af[mf] = *reinterpret_cast<const short8*>(&As[r * 64 + (blk << 3)]);
      }
#pragma unroll
      for (int nf = 0; nf < 4; ++nf) {
        int r = wc * 64 + nf * 16 + rr;
        int blk = (kk * 4 + g) ^ (r & 7);
        bfr[nf] = *reinterpret_cast<const short8*>(&Bs[r * 64 + (blk << 3)]);
      }
#pragma unroll
      for (int mf = 0; mf < 4; ++mf)
#pragma unroll
        for (int nf = 0; nf < 4; ++nf)
          acc[mf][nf] = __builtin_amdgcn_mfma_f32_16x16x32_bf16(af[mf], bfr[nf], acc[mf][nf], 0, 0, 0);
    }
  }

#pragma unroll
  for (int mf = 0; mf < 4; ++mf) {
#pragma unroll
    for (int rg = 0; rg < 4; ++rg) {
      int lrow = wr * 64 + mf * 16 + g * 4 + rg;
      float s = 0.f;
#pragma unroll
      for (int nf = 0; nf < 4; ++nf) s += fast_tanh(acc[mf][nf][rg]) * vreg[nf];
      s += __shfl_xor(s, 1);
      s += __shfl_xor(s, 2);
      s += __shfl_xor(s, 4);
      s += __shfl_xor(s, 8);
      if (rr == 0) red[wc][lrow] = s;
    }
  }
  __syncthreads();
  if (tid < 128) {
    int row = row0 + tid;
    pl[((size_t)nblk << 16) + ((size_t)(row & 31) << 11) + (row >> 5)] =
        red[0][tid] + red[1][tid];
  }
}

// ---- variant B (fallback, small ws): exact R3 kernel — A fp32->cvt->ds_write ----
__global__ __launch_bounds__(256, 3) void k_logits_cvt(const float* __restrict__ enc,
                                                       const unsigned short* __restrict__ WT,
                                                       const float* __restrict__ qv,
                                                       const float* __restrict__ v,
                                                       float* __restrict__ pl) {
  __shared__ __align__(16) unsigned short As[128 * 64];
  __shared__ __align__(16) unsigned short Bs[128 * 64];
  __shared__ float red[2][128];

  const int tid = threadIdx.x;
  const int xcd = blockIdx.x & 7, slot = blockIdx.x >> 3;
  const int nblk = slot & 7;
  const int mblk = xcd + ((slot >> 3) << 3);
  const int row0 = mblk << 7;
  const int n0 = nblk << 7;

  const int w = tid >> 6, lane = tid & 63;
  const int wr = w >> 1, wc = w & 1;
  const int g = lane >> 4, rr = lane & 15;

  float vreg[4];
#pragma unroll
  for (int nf = 0; nf < 4; ++nf) vreg[nf] = v[n0 + wc * 64 + nf * 16 + rr];

  f32x4 acc[4][4];
#pragma unroll
  for (int mf = 0; mf < 4; ++mf)
#pragma unroll
    for (int nf = 0; nf < 4; ++nf)
#pragma unroll
      for (int rg = 0; rg < 4; ++rg) {
        int b = ((mf & 1) << 4) + (g << 2) + rg;
        acc[mf][nf][rg] = qv[((size_t)b << 10) + n0 + wc * 64 + nf * 16 + rr];
      }

  const int ar = tid >> 4;
  const int ac4 = tid & 15;
  const int ablk = ((ac4 >> 1) ^ (ar & 7));
  const int brow = lane >> 3, bjj = lane & 7;

  for (int kt = 0; kt < 16; ++kt) {
    const int k0 = kt << 6;
    __syncthreads();
#pragma unroll
    for (int c = 0; c < 4; ++c) {
      int nrow = w * 32 + c * 8 + brow;
      int blk = bjj ^ (brow & 7);
      const char* src = (const char*)WT + (((size_t)(n0 + nrow) << 10) + k0) * 2 + (blk << 4);
      load_lds16(src, (void*)&Bs[(w * 32 + c * 8) * 64]);
    }
#pragma unroll
    for (int i = 0; i < 8; ++i) {
      int r = ar + (i << 4);
      f32x4 a4 = *reinterpret_cast<const f32x4*>(enc + (((size_t)(row0 + r)) << 10) + k0 + (ac4 << 2));
      bf16x4 pk = {(__bf16)a4.x, (__bf16)a4.y, (__bf16)a4.z, (__bf16)a4.w};
      *reinterpret_cast<bf16x4*>(&As[r * 64 + (ablk << 3) + ((ac4 & 1) << 2)]) = pk;
    }
    __syncthreads();
#pragma unroll
    for (int kk = 0; kk < 2; ++kk) {
      short8 af[4], bfr[4];
#pragma unroll
      for (int mf = 0; mf < 4; ++mf) {
        int r = wr * 64 + mf * 16 + rr;
        int blk = (kk * 4 + g) ^ (r & 7);
        af[mf] = *reinterpret_cast<const short8*>(&As[r * 64 + (blk << 3)]);
      }
#pragma unroll
      for (int nf = 0; nf < 4; ++nf) {
        int r = wc * 64 + nf * 16 + rr;
        int blk = (kk * 4 + g) ^ (r & 7);
        bfr[nf] = *reinterpret_cast<const short8*>(&Bs[r * 64 + (blk << 3)]);
      }
#pragma unroll
      for (int mf = 0; mf < 4; ++mf)
#pragma unroll
        for (int nf = 0; nf < 4; ++nf)
          acc[mf][nf] = __builtin_amdgcn_mfma_f32_16x16x32_bf16(af[mf], bfr[nf], acc[mf][nf], 0, 0, 0);
    }
  }

#pragma unroll
  for (int mf = 0; mf < 4; ++mf) {
#pragma unroll
    for (int rg = 0; rg < 4; ++rg) {
      int lrow = wr * 64 + mf * 16 + g * 4 + rg;
      float s = 0.f;
#pragma unroll
      for (int nf = 0; nf < 4; ++nf) s += fast_tanh(acc[mf][nf][rg]) * vreg[nf];
      s += __shfl_xor(s, 1);
      s += __shfl_xor(s, 2);
      s += __shfl_xor(s, 4);
      s += __shfl_xor(s, 8);
      if (rr == 0) red[wc][lrow] = s;
    }
  }
  __syncthreads();
  if (tid < 128) {
    int row = row0 + tid;
    pl[((size_t)nblk << 16) + ((size_t)(row & 31) << 11) + (row >> 5)] =
        red[0][tid] + red[1][tid];
  }
}

// ---------------- softmax over l, per b ------------------------------------------
__global__ __launch_bounds__(256) void k_softmax(const float* __restrict__ pl,
                                                 const float* __restrict__ mask,
                                                 float* __restrict__ al) {
  const int b = blockIdx.x, t = threadIdx.x;
  __shared__ float sr[256];
  float lg[8];
  float mx = -3.4e38f;
#pragma unroll
  for (int i = 0; i < 8; ++i) {
    int l = t + (i << 8);
    float s = mask[(l << 5) + b];
#pragma unroll
    for (int nb = 0; nb < 8; ++nb) s += pl[((size_t)nb << 16) + (b << 11) + l];
    lg[i] = s;
    mx = fmaxf(mx, s);
  }
  sr[t] = mx;
  __syncthreads();
  for (int off = 128; off > 0; off >>= 1) {
    if (t < off) sr[t] = fmaxf(sr[t], sr[t + off]);
    __syncthreads();
  }
  const float M = sr[0];
  __syncthreads();
  float sum = 0.f;
#pragma unroll
  for (int i = 0; i < 8; ++i) {
    lg[i] = __expf(lg[i] - M);
    sum += lg[i];
  }
  sr[t] = sum;
  __syncthreads();
  for (int off = 128; off > 0; off >>= 1) {
    if (t < off) sr[t] += sr[t + off];
    __syncthreads();
  }
  const float inv = 1.f / sr[0];
#pragma unroll
  for (int i = 0; i < 8; ++i) {
    int l = t + (i << 8);
    al[(l << 5) + b] = lg[i] * inv;
  }
}

// ---------------- context partials from bf16 enc: grid = 32 chunks x 32 b --------
__global__ __launch_bounds__(256) void k_ctx_bf(const unsigned short* __restrict__ encB,
                                                const float* __restrict__ al,
                                                float* __restrict__ pctx) {
  const int b = blockIdx.x & 31, ch = blockIdx.x >> 5;
  const int t = threadIdx.x;
  __shared__ float wl[64];
  if (t < 64) wl[t] = al[(((ch << 6) + t) << 5) + b];
  __syncthreads();
  f32x4 acc = (f32x4){0.f, 0.f, 0.f, 0.f};
  const unsigned short* base = encB + (((size_t)ch * 2048 + b) << 10) + (t << 2);
#pragma unroll 8
  for (int i = 0; i < 64; ++i) {
    short4v e = *reinterpret_cast<const short4v*>(base + (size_t)i * 32768);
    float w = wl[i];
    acc.x = fmaf(w, bf2f((unsigned short)e[0]), acc.x);
    acc.y = fmaf(w, bf2f((unsigned short)e[1]), acc.y);
    acc.z = fmaf(w, bf2f((unsigned short)e[2]), acc.z);
    acc.w = fmaf(w, bf2f((unsigned short)e[3]), acc.w);
  }
  *reinterpret_cast<f32x4*>(((float*)pctx) + ((size_t)blockIdx.x << 10) + (t << 2)) = acc;
}

// ---------------- context partials fp32 (fallback path) --------------------------
__global__ __launch_bounds__(256) void k_ctx(const float* __restrict__ enc,
                                             const float* __restrict__ al,
                                             float* __restrict__ pctx) {
  const int b = blockIdx.x & 31, ch = blockIdx.x >> 5;
  const int t = threadIdx.x;
  __shared__ float wl[64];
  if (t < 64) wl[t] = al[(((ch << 6) + t) << 5) + b];
  __syncthreads();
  f32x4 acc = (f32x4){0.f, 0.f, 0.f, 0.f};
  const float* base = enc + (((size_t)ch * 2048 + b) << 10) + (t << 2);
#pragma unroll 8
  for (int i = 0; i < 64; ++i) {
    f32x4 e = *reinterpret_cast<const f32x4*>(base + (size_t)i * 32768);
    acc += wl[i] * e;
  }
  *reinterpret_cast<f32x4*>(((float*)pctx) + ((size_t)blockIdx.x << 10) + (t << 2)) = acc;
}

__global__ __launch_bounds__(256) void k_ctxred(const float* __restrict__ pctx,
                                                float* __restrict__ out) {
  int i = blockIdx.x * 256 + threadIdx.x;  // 32768 = b*1024 + e
  int b = i >> 10, e = i & 1023;
  float s = 0.f;
#pragma unroll
  for (int ch = 0; ch < 32; ++ch) s += pctx[(size_t)((ch << 5) + b) * 1024 + e];
  out[i] = s;
}

extern "C" void kernel_launch(void* const* d_in, const int* in_sizes, int n_in,
                              void* d_out, int out_size, void* d_ws, size_t ws_size,
                              hipStream_t stream) {
  const float* enc = (const float*)d_in[0];
  const float* mask = (const float*)d_in[1];
  const float* hidden = (const float*)d_in[2];
  const float* Wenc = (const float*)d_in[3];
  const float* battn = (const float*)d_in[4];
  const float* Whid = (const float*)d_in[5];
  const float* v = (const float*)d_in[6];
  float* out = (float*)d_out;          // [0,32768) context [B][ENC]; [32768,98304) alignment [L][B]
  char* ws = (char*)d_ws;

  const bool big = ws_size >= (size_t)140 * 1024 * 1024;
  char* base = big ? ws + ((size_t)128 << 20) : ws;
  unsigned short* encB = (unsigned short*)ws;                       // 128 MB (big only)
  unsigned short* WT = (unsigned short*)base;                       // 2 MB
  float* q = (float*)(base + (2u << 20));                           // 128 KB
  float* pq = (float*)(base + (2u << 20) + (128u << 10));           // 1 MB
  float* pl = (float*)(base + (3u << 20) + (128u << 10));           // 2 MB
  float* pctx = (float*)(base + (5u << 20) + (128u << 10));         // 4 MB
  float* align_out = out + 32768;

  k_wt<<<256, 256, 0, stream>>>(Wenc, WT);
  k_qpart<<<64, 128, 0, stream>>>(hidden, Whid, pq);
  k_qred<<<128, 256, 0, stream>>>(pq, battn, q);
  if (big) {
    k_enc_bf16<<<2048, 256, 0, stream>>>(enc, encB);
    k_logits_bf<<<4096, 256, 0, stream>>>(encB, WT, q, v, pl);
  } else {
    k_logits_cvt<<<4096, 256, 0, stream>>>(enc, WT, q, v, pl);
  }
  k_softmax<<<32, 256, 0, stream>>>(pl, mask, align_out);
  if (big) {
    k_ctx_bf<<<1024, 256, 0, stream>>>(encB, align_out, pctx);
  } else {
    k_ctx<<<1024, 256, 0, stream>>>(enc, align_out, pctx);
  }
  k_ctxred<<<128, 256, 0, stream>>>(pctx, out);
}